// Round 18
// baseline (678.252 us; speedup 1.0000x reference)
//
#include <hip/hip_runtime.h>
#include <hip/hip_bf16.h>
#include <cstdint>

// ---------------------------------------------------------------------------
// Qwen3.5 GatedDeltaNet — round 18: recur barrier reduction (4 -> 3 per
// chunk): Klds/Wlds double-buffered by chunk parity, eGC hoisted to a
// register, B4 removed (race-audited: P1' write-set disjoint from P4
// read-set). All other kernels unchanged from round 17 (674 us, 0.0234).
// ---------------------------------------------------------------------------

#define HSZ 2048
#define NUM_K_HEADS 16
#define NUM_V_HEADS 32
#define DKH 128
#define DVH 128
#define KEY_DIM 2048
#define VALUE_DIM 4096
#define CONV_DIM 8192
#define BB 2
#define SSEQ 2048
#define MM (BB * SSEQ) /* 4096 rows */
#define CHUNK 64
#define NCHUNK (SSEQ / CHUNK) /* 32 */
#define DVB 16 /* v-cols per recur block */

typedef __hip_bfloat16 bf16;
typedef short short8 __attribute__((ext_vector_type(8)));
typedef float f32x4 __attribute__((ext_vector_type(4)));

__device__ __forceinline__ float bfu(ushort u) {
  union { float f; uint32_t i; } x;
  x.i = ((uint32_t)u) << 16;
  return x.f;
}
__device__ __forceinline__ ushort f2b(float f) {
  bf16 h = __float2bfloat16(f);
  return *reinterpret_cast<ushort*>(&h);
}

__device__ __forceinline__ void gload16(const void* g, const void* l) {
  __builtin_amdgcn_global_load_lds(
      (const __attribute__((address_space(1))) unsigned int*)g,
      (__attribute__((address_space(3))) unsigned int*)(const_cast<void*>(l)),
      16, 0, 0);
}

// swizzled LDS indexers (break D=128/D=64 row-major bank pathology)
__device__ __forceinline__ int kidx(int r, int d) {  // [*][128] bf16
  return r * 128 + (((d >> 3) ^ (r & 7)) << 3) + (d & 7);
}
__device__ __forceinline__ int widx(int r, int d) {  // [*][64] bf16
  return r * 64 + (((d >> 3) ^ (r & 7)) << 3) + (d & 7);
}

// ---------------- prep: cast hs + transpose 3 weights (one dispatch) -------
__device__ __forceinline__ void tc_tile(const float* __restrict__ W,
                                        ushort* __restrict__ WT, int K, int N,
                                        int n0, int k0, int t,
                                        ushort (*tile)[33]) {
  const int tx = t & 31, ty = t >> 5;
#pragma unroll
  for (int i = 0; i < 4; ++i)
    tile[ty + i * 8][tx] = f2b(W[(size_t)(k0 + ty + i * 8) * N + n0 + tx]);
  __syncthreads();
#pragma unroll
  for (int i = 0; i < 4; ++i)
    WT[(size_t)(n0 + ty + i * 8) * K + k0 + tx] = tile[tx][ty + i * 8];
}

__global__ __launch_bounds__(256) void prep_kernel(
    const float* __restrict__ hs, const float* __restrict__ w_qkv,
    const float* __restrict__ w_z, const float* __restrict__ w_out,
    ushort* __restrict__ hs_b, ushort* __restrict__ wqkvT,
    ushort* __restrict__ wzT, ushort* __restrict__ woutT) {
  __shared__ ushort tile[32][33];
  const int bid = blockIdx.x;
  const int t = threadIdx.x;
  if (bid < 8192) {  // cast: MM*HSZ/4 = 2M float4, exactly 8192 blocks
    const int i = bid * 256 + t;
    float4 v = ((const float4*)hs)[i];
    ushort4 u;
    u.x = f2b(v.x); u.y = f2b(v.y); u.z = f2b(v.z); u.w = f2b(v.w);
    ((ushort4*)hs_b)[i] = u;
  } else if (bid < 8192 + 16384) {  // w_qkv: [2048,8192] -> [8192,2048]
    const int idx = bid - 8192;
    tc_tile(w_qkv, wqkvT, HSZ, CONV_DIM, (idx & 255) * 32, (idx >> 8) * 32, t,
            tile);
  } else if (bid < 8192 + 16384 + 8192) {  // w_z: [2048,4096] -> [4096,2048]
    const int idx = bid - 24576;
    tc_tile(w_z, wzT, HSZ, VALUE_DIM, (idx & 127) * 32, (idx >> 7) * 32, t,
            tile);
  } else {  // w_out: [4096,2048] -> [2048,4096]
    const int idx = bid - 32768;
    tc_tile(w_out, woutT, VALUE_DIM, HSZ, (idx & 63) * 32, (idx >> 6) * 32, t,
            tile);
  }
}

// ---------------- fused 256^2 bf16 MFMA GEMM (mixed | z) -------------------
// BK=32, 4-buffer ring, stage-in-compute-region, vmcnt(4), 1 barrier/tile.
__global__ __launch_bounds__(512) void gemm256_fused(
    const ushort* __restrict__ A, const ushort* __restrict__ BT,
    ushort* __restrict__ Cm, ushort* __restrict__ Cz, int M, int K) {
  __shared__ __align__(16) ushort smem[256 * 264];  // >= 4 bufs x 16384
  const int t = threadIdx.x;
  const int w = t >> 6, lane = t & 63;
  const int m0 = blockIdx.y * 256, n0 = blockIdx.x * 256;
  const int wm = (w >> 2) * 128, wn = (w & 3) * 64;
  const int fr = lane & 15, kb = lane >> 4;  // kb = k-granule 0..3
  const int srow = t >> 2;                   // 0..127
  const int sg = t & 3;                      // staging granule
  const int ssw = ((sg ^ ((srow >> 1) & 3)) << 3);  // pre-swizzled src col
  f32x4 acc[8][4] = {};
  const int nt = K / 32;

#define STAGE_F(tt, buf)                                                      \
  {                                                                           \
    const int k0_ = (tt)*32;                                                  \
    ushort* As_ = smem + (buf)*16384;                                         \
    ushort* Bs_ = As_ + 8192;                                                 \
    _Pragma("unroll") for (int p = 0; p < 2; ++p) {                           \
      const int row_ = p * 128 + srow;                                        \
      gload16(&A[(size_t)(m0 + row_) * K + k0_ + ssw],                        \
              &As_[row_ * 32 + sg * 8]);                                      \
    }                                                                         \
    _Pragma("unroll") for (int p = 0; p < 2; ++p) {                           \
      const int row_ = p * 128 + srow;                                        \
      gload16(&BT[(size_t)(n0 + row_) * K + k0_ + ssw],                       \
              &Bs_[row_ * 32 + sg * 8]);                                      \
    }                                                                         \
  }

  STAGE_F(0, 0);
  STAGE_F(1, 1);

  for (int tt = 0; tt < nt; ++tt) {
    const int buf = tt & 3;
    if (tt + 1 < nt)
      asm volatile("s_waitcnt vmcnt(4)" ::: "memory");
    else
      asm volatile("s_waitcnt vmcnt(0)" ::: "memory");
    __builtin_amdgcn_sched_barrier(0);
    __builtin_amdgcn_s_barrier();  // tile tt landed for all waves
    __builtin_amdgcn_sched_barrier(0);
    if (tt + 2 < nt) STAGE_F(tt + 2, (tt + 2) & 3);  // overlaps compute
    const ushort* As = smem + buf * 16384;
    const ushort* Bs = As + 8192;
    short8 af[8], bf_[4];
#pragma unroll
    for (int nf = 0; nf < 4; ++nf) {
      const int row = wn + nf * 16 + fr;
      bf_[nf] = *(const short8*)&Bs[row * 32 + ((kb ^ ((row >> 1) & 3)) << 3)];
    }
#pragma unroll
    for (int mf = 0; mf < 8; ++mf) {
      const int row = wm + mf * 16 + fr;
      af[mf] = *(const short8*)&As[row * 32 + ((kb ^ ((row >> 1) & 3)) << 3)];
    }
    __builtin_amdgcn_s_setprio(1);
#pragma unroll
    for (int mf = 0; mf < 8; ++mf)
#pragma unroll
      for (int nf = 0; nf < 4; ++nf)
        acc[mf][nf] = __builtin_amdgcn_mfma_f32_16x16x32_bf16(
            af[mf], bf_[nf], acc[mf][nf], 0, 0, 0);
    __builtin_amdgcn_s_setprio(0);
  }
#undef STAGE_F

  __syncthreads();  // all reads done before epilogue overwrites smem
  const int crow = wm + (lane >> 4) * 4;
  const int ccol = wn + fr;
#pragma unroll
  for (int mf = 0; mf < 8; ++mf)
#pragma unroll
    for (int nf = 0; nf < 4; ++nf)
#pragma unroll
      for (int j = 0; j < 4; ++j)
        smem[(crow + mf * 16 + j) * 264 + ccol + nf * 16] = f2b(acc[mf][nf][j]);
  __syncthreads();
  ushort* Cout = (n0 < CONV_DIM) ? Cm : Cz;
  const int Nout = (n0 < CONV_DIM) ? CONV_DIM : VALUE_DIM;
  const int ncol = (n0 < CONV_DIM) ? n0 : n0 - CONV_DIM;
#pragma unroll
  for (int p = 0; p < 16; ++p) {
    const int r = p * 16 + (t >> 5), cch = (t & 31) * 8;
    *(short8*)&Cout[(size_t)(m0 + r) * Nout + ncol + cch] =
        *(const short8*)&smem[r * 264 + cch];
  }
}

// ---------------- 128^2 bf16 MFMA GEMM (fp32 out), BK=32 4-buffer ring -----
__global__ __launch_bounds__(256, 2) void gemm128_f32(
    const ushort* __restrict__ A, const ushort* __restrict__ BT,
    float* __restrict__ C, int M, int N, int K) {
  __shared__ __align__(16) ushort smem[4 * 8192];  // 64 KiB
  const int t = threadIdx.x;
  const int w = t >> 6, lane = t & 63;
  const int m0 = blockIdx.y * 128, n0 = blockIdx.x * 128;
  const int wm = (w >> 1) * 64, wn = (w & 1) * 64;
  const int fr = lane & 15, kb = lane >> 4;
  const int srow = t >> 2;  // 0..63
  const int sg = t & 3;
  const int ssw = ((sg ^ ((srow >> 1) & 3)) << 3);
  f32x4 acc[4][4] = {};
  const int nt = K / 32;

#define STAGE_G(tt, buf)                                                      \
  {                                                                           \
    const int k0_ = (tt)*32;                                                  \
    ushort* As_ = smem + (buf)*8192;                                          \
    ushort* Bs_ = As_ + 4096;                                                 \
    _Pragma("unroll") for (int p = 0; p < 2; ++p) {                           \
      const int row_ = p * 64 + srow;                                         \
      gload16(&A[(size_t)(m0 + row_) * K + k0_ + ssw],                        \
              &As_[row_ * 32 + sg * 8]);                                      \
    }                                                                         \
    _Pragma("unroll") for (int p = 0; p < 2; ++p) {                           \
      const int row_ = p * 64 + srow;                                         \
      gload16(&BT[(size_t)(n0 + row_) * K + k0_ + ssw],                       \
              &Bs_[row_ * 32 + sg * 8]);                                      \
    }                                                                         \
  }

  STAGE_G(0, 0);
  STAGE_G(1, 1);

  for (int tt = 0; tt < nt; ++tt) {
    const int buf = tt & 3;
    if (tt + 1 < nt)
      asm volatile("s_waitcnt vmcnt(4)" ::: "memory");
    else
      asm volatile("s_waitcnt vmcnt(0)" ::: "memory");
    __builtin_amdgcn_sched_barrier(0);
    __builtin_amdgcn_s_barrier();
    __builtin_amdgcn_sched_barrier(0);
    if (tt + 2 < nt) STAGE_G(tt + 2, (tt + 2) & 3);
    const ushort* As = smem + buf * 8192;
    const ushort* Bs = As + 4096;
    short8 af[4], bfr[4];
#pragma unroll
    for (int nf = 0; nf < 4; ++nf) {
      const int row = wn + nf * 16 + fr;
      bfr[nf] = *(const short8*)&Bs[row * 32 + ((kb ^ ((row >> 1) & 3)) << 3)];
    }
#pragma unroll
    for (int mf = 0; mf < 4; ++mf) {
      const int row = wm + mf * 16 + fr;
      af[mf] = *(const short8*)&As[row * 32 + ((kb ^ ((row >> 1) & 3)) << 3)];
    }
    __builtin_amdgcn_s_setprio(1);
#pragma unroll
    for (int mf = 0; mf < 4; ++mf)
#pragma unroll
      for (int nf = 0; nf < 4; ++nf)
        acc[mf][nf] = __builtin_amdgcn_mfma_f32_16x16x32_bf16(
            af[mf], bfr[nf], acc[mf][nf], 0, 0, 0);
    __builtin_amdgcn_s_setprio(0);
  }
#undef STAGE_G

  const int orow = m0 + wm + (lane >> 4) * 4;
  const int ocol = n0 + wn + fr;
#pragma unroll
  for (int mf = 0; mf < 4; ++mf)
#pragma unroll
    for (int nf = 0; nf < 4; ++nf)
#pragma unroll
      for (int j = 0; j < 4; ++j)
        C[(size_t)(orow + mf * 16 + j) * N + ocol + nf * 16] = acc[mf][nf][j];
}

// ---------------- b/a projections + gates (8 rows/block) -------------------
__global__ __launch_bounds__(256) void ba_kernel(
    const float* __restrict__ hs, const float* __restrict__ w_b,
    const float* __restrict__ w_a, const float* __restrict__ dt_bias,
    const float* __restrict__ A_log, float* __restrict__ gbuf,
    float* __restrict__ beta) {
  const int row0 = blockIdx.x * 8;
  const int t = threadIdx.x;
  __shared__ float hsr[8][HSZ];  // 64 KB
  __shared__ float red[2][256];
  {
    const float4* src = (const float4*)(hs + (size_t)row0 * HSZ);
    for (int i = t; i < 8 * HSZ / 4; i += 256) ((float4*)hsr)[i] = src[i];
  }
  __syncthreads();
  const int h = t & 31, p = t >> 5;  // head, partial (8 over k)
  float sb[8] = {}, sa[8] = {};
  const int kbeg = p * 256;
  for (int k = kbeg; k < kbeg + 256; ++k) {
    float wb = w_b[k * NUM_V_HEADS + h];
    float wa = w_a[k * NUM_V_HEADS + h];
#pragma unroll
    for (int r = 0; r < 8; ++r) {
      float x = hsr[r][k];
      sb[r] += x * wb;
      sa[r] += x * wa;
    }
  }
#pragma unroll
  for (int r = 0; r < 8; ++r) {
    red[0][t] = sb[r];
    red[1][t] = sa[r];
    __syncthreads();
    if (t < NUM_V_HEADS) {
      float b = 0.f, a = 0.f;
#pragma unroll
      for (int q = 0; q < 8; ++q) {
        b += red[0][t + 32 * q];
        a += red[1][t + 32 * q];
      }
      float bet = 1.f / (1.f + expf(-b));
      float x = a + dt_bias[t];
      float sp = (x > 20.f) ? x : log1pf(expf(x));
      gbuf[(size_t)(row0 + r) * NUM_V_HEADS + t] = -expf(A_log[t]) * sp;
      beta[(size_t)(row0 + r) * NUM_V_HEADS + t] = bet;
    }
    __syncthreads();
  }
}

// ---------------- causal conv + silu + l2norm (row-tiled, rolling window) --
__global__ __launch_bounds__(256) void conv_kernel(
    const ushort* __restrict__ mixed, const float* __restrict__ conv_w,
    ushort* __restrict__ qkv) {
  const int bid = blockIdx.x;
  const int slice = bid & 3;
  const int row0 = (bid >> 2) * 8;
  const int s0 = row0 & (SSEQ - 1);
  const int t = threadIdx.x;
  const int cbase = slice * 2048 + t * 8;

  float wreg[4][8];
#pragma unroll
  for (int e = 0; e < 8; ++e) {
    float4 wv = *(const float4*)&conv_w[(cbase + e) * 4];
    wreg[0][e] = wv.x;
    wreg[1][e] = wv.y;
    wreg[2][e] = wv.z;
    wreg[3][e] = wv.w;
  }

  const ushort* mp = mixed + (size_t)row0 * CONV_DIM + cbase;
  short8 win[4];
  const short8 z8 = {0, 0, 0, 0, 0, 0, 0, 0};
#pragma unroll
  for (int j = 0; j < 3; ++j)
    win[j] = (s0 - 3 + j >= 0) ? *(const short8*)&mp[(ptrdiff_t)(j - 3) * CONV_DIM]
                               : z8;

  if (slice < 2) {
    float vals[8][8];
    float ssq[8];
#pragma unroll
    for (int r = 0; r < 8; ++r) {
      win[3] = *(const short8*)&mp[(ptrdiff_t)r * CONV_DIM];
      float sq = 0.f;
#pragma unroll
      for (int e = 0; e < 8; ++e) {
        float a = bfu((ushort)win[0][e]) * wreg[0][e] +
                  bfu((ushort)win[1][e]) * wreg[1][e] +
                  bfu((ushort)win[2][e]) * wreg[2][e] +
                  bfu((ushort)win[3][e]) * wreg[3][e];
        float x = a / (1.f + expf(-a));
        vals[r][e] = x;
        sq += x * x;
      }
      ssq[r] = sq;
      win[0] = win[1];
      win[1] = win[2];
      win[2] = win[3];
    }
#pragma unroll
    for (int r = 0; r < 8; ++r) {
      float sq = ssq[r];
      sq += __shfl_xor(sq, 1, 64);
      sq += __shfl_xor(sq, 2, 64);
      sq += __shfl_xor(sq, 4, 64);
      sq += __shfl_xor(sq, 8, 64);
      float sc = rsqrtf(sq + 1e-6f);
      if (slice == 0) sc *= 0.08838834764831845f;
      short8 o;
#pragma unroll
      for (int e = 0; e < 8; ++e) o[e] = (short)f2b(vals[r][e] * sc);
      *(short8*)&qkv[(size_t)(row0 + r) * CONV_DIM + cbase] = o;
    }
  } else {
#pragma unroll
    for (int r = 0; r < 8; ++r) {
      win[3] = *(const short8*)&mp[(ptrdiff_t)r * CONV_DIM];
      short8 o;
#pragma unroll
      for (int e = 0; e < 8; ++e) {
        float a = bfu((ushort)win[0][e]) * wreg[0][e] +
                  bfu((ushort)win[1][e]) * wreg[1][e] +
                  bfu((ushort)win[2][e]) * wreg[2][e] +
                  bfu((ushort)win[3][e]) * wreg[3][e];
        o[e] = (short)f2b(a / (1.f + expf(-a)));
      }
      *(short8*)&qkv[(size_t)(row0 + r) * CONV_DIM + cbase] = o;
      win[0] = win[1];
      win[1] = win[2];
      win[2] = win[3];
    }
  }
}

// ---------------- stage 1: per-chunk T = (I+A)^{-1} and W ------------------
// grid = 2048; Q direct-to-reg (no Qlds) -> ~41 KB LDS, 3 blocks/CU.
__global__ __launch_bounds__(256) void chunk_T_kernel(
    const ushort* __restrict__ qkv, const float* __restrict__ gbuf,
    const float* __restrict__ beta, ushort* __restrict__ Tbuf,
    ushort* __restrict__ Wbuf) {
  const int bid = blockIdx.x;
  const int c = bid & 31;
  const int h = (bid >> 5) & 31;
  const int b = bid >> 10;
  const int hk = h >> 1;
  const int t = threadIdx.x;
  const int w = t >> 6, lane = t & 63;
  const int fr = lane & 15, fq = lane >> 4;

  __shared__ ushort Klds[64 * 128];           // 16 KB
  __shared__ __align__(16) float AT[64][68];  // 17.4 KB
  __shared__ ushort Wlds[64 * 64];            // 8 KB
  __shared__ float Gs[64], Bsh[64];

  const int row0 = b * SSEQ + c * CHUNK;
  const int qcol = hk * DKH;
  const int kcol = KEY_DIM + hk * DKH;

  // Q fragments direct to registers (same values the old Qlds round-trip gave)
  short8 xq[4];
#pragma unroll
  for (int ks = 0; ks < 4; ++ks)
    xq[ks] = *(const short8*)&qkv[(size_t)(row0 + w * 16 + fr) * CONV_DIM +
                                  qcol + ks * 32 + fq * 8];
#pragma unroll
  for (int r = 0; r < 4; ++r) {
    int vi = t + 256 * r;
    int row = vi >> 4, gr = vi & 15;
    *(short8*)&Klds[row * 128 + ((gr ^ (row & 7)) << 3)] =
        *(const short8*)&qkv[(size_t)(row0 + row) * CONV_DIM + kcol + gr * 8];
  }
  if (t < 64) {
    float s = gbuf[(size_t)(row0 + t) * NUM_V_HEADS + h];
#pragma unroll
    for (int off = 1; off < 64; off <<= 1) {
      float p = __shfl_up(s, off, 64);
      if (lane >= off) s += p;
    }
    Gs[t] = s;
    Bsh[t] = beta[(size_t)(row0 + t) * NUM_V_HEADS + h];
  }
  __syncthreads();

  f32x4 kkt[4] = {}, qkt[4] = {};
#pragma unroll
  for (int ks = 0; ks < 4; ++ks) {
    int d0 = ks * 32 + fq * 8;
    short8 xk = *(const short8*)&Klds[kidx(w * 16 + fr, d0)];
#pragma unroll
    for (int j = 0; j < 4; ++j) {
      short8 yk = *(const short8*)&Klds[kidx(j * 16 + fr, d0)];
      kkt[j] = __builtin_amdgcn_mfma_f32_16x16x32_bf16(xk, yk, kkt[j], 0, 0, 0);
      qkt[j] = __builtin_amdgcn_mfma_f32_16x16x32_bf16(xq[ks], yk, qkt[j], 0, 0, 0);
    }
  }
#pragma unroll
  for (int j = 0; j < 4; ++j)
#pragma unroll
    for (int jj = 0; jj < 4; ++jj) {
      int i = w * 16 + fq * 4 + jj;
      int jc = j * 16 + fr;
      AT[jc][i] = (jc < i) ? Bsh[i] * __expf(Gs[i] - Gs[jc]) * kkt[j][jj] : 0.f;
      float val = (jc <= i) ? __expf(Gs[i] - Gs[jc]) * qkt[j][jj] : 0.f;
      Wlds[widx(i, jc)] = f2b(val);
    }
  __syncthreads();

  {
    ushort* Wg = Wbuf + (size_t)bid * 4096;
#pragma unroll
    for (int e = 0; e < 8; ++e)
      ((uint*)Wg)[e * 256 + t] = ((const uint*)Wlds)[e * 256 + t];
  }

  if (w == 0) {
    float u[64];
#pragma unroll
    for (int i = 0; i < 64; ++i) u[i] = (i == lane) ? 1.f : 0.f;
#pragma unroll
    for (int j = 0; j < 63; ++j) {
      float xj = u[j];
      const int i0 = (j + 1) & ~3;
#pragma unroll
      for (int ii = i0; ii < 64; ii += 4) {
        float4 a4 = *(const float4*)&AT[j][ii];
        if (ii + 0 > j) u[ii + 0] -= a4.x * xj;
        if (ii + 1 > j) u[ii + 1] -= a4.y * xj;
        if (ii + 2 > j) u[ii + 2] -= a4.z * xj;
        if (ii + 3 > j) u[ii + 3] -= a4.w * xj;
      }
    }
    ushort* Tg = Tbuf + (size_t)bid * 4096;
#pragma unroll
    for (int i = 0; i < 64; ++i) Tg[i * 64 + lane] = f2b(u[i]);
  }
}

// ---------------- stage 2: sequential chunk loop, 3 barriers/chunk ---------
__global__ __launch_bounds__(256, 2) void recur_chunk_kernel(
    const ushort* __restrict__ qkv, const float* __restrict__ gbuf,
    const float* __restrict__ beta, const ushort* __restrict__ Tbuf,
    const ushort* __restrict__ Wbuf, float* __restrict__ o) {
  const int bid = blockIdx.x;
  const int dvq = bid & 7;
  const int h = (bid >> 3) & 31;
  const int b = bid >> 8;
  const int hk = h >> 1;
  const int t = threadIdx.x;
  const int w = t >> 6, lane = t & 63;
  const int fr = lane & 15, fq = lane >> 4;

  __shared__ ushort Klds[2][64 * 128];  // 32 KB (chunk-parity dbuf)
  __shared__ ushort Wlds[2][64 * 64];   // 16 KB (chunk-parity dbuf)
  __shared__ ushort Vlds[64 * DVB];     // 2 KB
  __shared__ ushort Sth[DVB * 128];     // 4 KB
  __shared__ ushort Stl[DVB * 128];     // 4 KB
  __shared__ ushort Th[64 * 64];        // 8 KB
  __shared__ ushort Ut[DVB * 64];       // 2 KB
  __shared__ ushort UTs[DVB * 64];      // 2 KB
  __shared__ ushort UTo[DVB * 64];      // 2 KB
  __shared__ float Gs[64], Bsh[64];

  float sreg[2][4] = {};

  const int qcol = hk * DKH;
  const int kcol = KEY_DIM + hk * DKH;
  const int vcol = 2 * KEY_DIM + h * DVH + dvq * DVB;
  const int ocol = h * DVH + dvq * DVB;
  const size_t tbase0 = ((size_t)(b * 32 + h) * 32) * 4096;

  short8 pK[4], pT0, pT1, pV, pxq[4];
  uint pW[8];
  float pg = 0.f, pb = 0.f;

  auto prefetch = [&](int c) {
    const int row0 = b * SSEQ + c * CHUNK;
#pragma unroll
    for (int ks = 0; ks < 4; ++ks)
      pxq[ks] = *(const short8*)&qkv[(size_t)(row0 + w * 16 + fr) * CONV_DIM +
                                     qcol + ks * 32 + fq * 8];
    const ushort* Tg = Tbuf + tbase0 + (size_t)c * 4096;
    const ushort* Wg = Wbuf + tbase0 + (size_t)c * 4096;
    pT0 = *(const short8*)&Tg[t * 16];
    pT1 = *(const short8*)&Tg[t * 16 + 8];
#pragma unroll
    for (int e = 0; e < 8; ++e) pW[e] = ((const uint*)Wg)[e * 256 + t];
#pragma unroll
    for (int r = 0; r < 4; ++r) {
      int vi = t + 256 * r;
      int row = vi >> 4, gr = vi & 15;
      pK[r] = *(const short8*)&qkv[(size_t)(row0 + row) * CONV_DIM + kcol + gr * 8];
    }
    if (t < 128) {
      int row = t >> 1, c0 = (t & 1) * 8;
      pV = *(const short8*)&qkv[(size_t)(row0 + row) * CONV_DIM + vcol + c0];
    }
    if (t < 64) {
      pg = gbuf[(size_t)(row0 + t) * NUM_V_HEADS + h];
      pb = beta[(size_t)(row0 + t) * NUM_V_HEADS + h];
    }
  };

  prefetch(0);

  for (int c = 0; c < NCHUNK; ++c) {
    const int row0 = b * SSEQ + c * CHUNK;
    const int cb = c & 1;

    // ---- P1: write prefetched regs to LDS (dbuf cb); gates; S->hi/lo ------
    short8 xq[4];
#pragma unroll
    for (int ks = 0; ks < 4; ++ks) xq[ks] = pxq[ks];
#pragma unroll
    for (int e = 0; e < 8; ++e) ((uint*)Wlds[cb])[e * 256 + t] = pW[e];
#pragma unroll
    for (int r = 0; r < 4; ++r) {
      int vi = t + 256 * r;
      int row = vi >> 4, gr = vi & 15;
      *(short8*)&Klds[cb][row * 128 + ((gr ^ (row & 7)) << 3)] = pK[r];
    }
    if (t < 128) {
      int row = t >> 1, c0 = (t & 1) * 8;
      *(short8*)&Vlds[row * DVB + c0] = pV;
    }
    if (t < 64) {
      float s = pg;
#pragma unroll
      for (int off = 1; off < 64; off <<= 1) {
        float p = __shfl_up(s, off, 64);
        if (lane >= off) s += p;
      }
      Gs[t] = s;
      Bsh[t] = pb;
    }
#pragma unroll
    for (int dt = 0; dt < 2; ++dt)
#pragma unroll
      for (int jj = 0; jj < 4; ++jj) {
        int d = (w * 2 + dt) * 16 + fq * 4 + jj;
        float f = sreg[dt][jj];
        ushort hi = f2b(f);
        int idx = kidx(fr, d);
        Sth[idx] = hi;
        Stl[idx] = f2b(f - bfu(hi));
      }
    {
      int r = t >> 2, d0 = (t & 3) * 16;
      *(short8*)&Th[widx(r, d0)] = pT0;
      *(short8*)&Th[widx(r, d0 + 8)] = pT1;
    }
    __syncthreads();  // B1

    if (c + 1 < NCHUNK) prefetch(c + 1);

    // eGC hoisted to a register (P4 must not read Gs: next P1 overwrites it)
    const float eGC = __expf(Gs[63]);

    // ---- P2: ks0, qs0; RHS -> Ut; oacc init -------------------------------
    f32x4 ks0 = {}, qs0 = {};
#pragma unroll
    for (int ks = 0; ks < 4; ++ks) {
      int d0 = ks * 32 + fq * 8;
      short8 xk = *(const short8*)&Klds[cb][kidx(w * 16 + fr, d0)];
      short8 yh = *(const short8*)&Sth[kidx(fr, d0)];
      short8 yl = *(const short8*)&Stl[kidx(fr, d0)];
      ks0 = __builtin_amdgcn_mfma_f32_16x16x32_bf16(xk, yh, ks0, 0, 0, 0);
      ks0 = __builtin_amdgcn_mfma_f32_16x16x32_bf16(xk, yl, ks0, 0, 0, 0);
      qs0 = __builtin_amdgcn_mfma_f32_16x16x32_bf16(xq[ks], yh, qs0, 0, 0, 0);
      qs0 = __builtin_amdgcn_mfma_f32_16x16x32_bf16(xq[ks], yl, qs0, 0, 0, 0);
    }
    f32x4 oacc;
#pragma unroll
    for (int jj = 0; jj < 4; ++jj) {
      int i = w * 16 + fq * 4 + jj;
      float eg = __expf(Gs[i]);
      float rhs = Bsh[i] * (bfu(Vlds[i * DVB + fr]) - eg * ks0[jj]);
      Ut[widx(fr, i)] = f2b(rhs);
      oacc[jj] = qs0[jj] * eg;
    }
    __syncthreads();  // B2

    // ---- P3: U = Th @ Ut (MFMA); write UTo / UTs --------------------------
    {
      f32x4 uacc = {};
#pragma unroll
      for (int ks = 0; ks < 2; ++ks) {
        int j0 = ks * 32 + fq * 8;
        short8 ta = *(const short8*)&Th[widx(w * 16 + fr, j0)];
        short8 ub = *(const short8*)&Ut[widx(fr, j0)];
        uacc = __builtin_amdgcn_mfma_f32_16x16x32_bf16(ta, ub, uacc, 0, 0, 0);
      }
#pragma unroll
      for (int jj = 0; jj < 4; ++jj) {
        int i = w * 16 + fq * 4 + jj;
        float u = uacc[jj];
        UTo[widx(fr, i)] = f2b(u);
        UTs[widx(fr, i)] = f2b(u * __expf(Gs[63] - Gs[i]));
      }
    }
    __syncthreads();  // B3

    // ---- P4: O = oacc + W@U; store; S := eGC*S + K^T @ Us -----------------
    // reads only Klds[cb]/Wlds[cb]/UTo/UTs + eGC reg -> safe vs next P1.
#pragma unroll
    for (int ks = 0; ks < 2; ++ks) {
      int i0 = ks * 32 + fq * 8;
      short8 xw = *(const short8*)&Wlds[cb][widx(w * 16 + fr, i0)];
      short8 yu = *(const short8*)&UTo[widx(fr, i0)];
      oacc = __builtin_amdgcn_mfma_f32_16x16x32_bf16(xw, yu, oacc, 0, 0, 0);
    }
#pragma unroll
    for (int jj = 0; jj < 4; ++jj) {
      int tt = w * 16 + fq * 4 + jj;
      o[(size_t)(row0 + tt) * VALUE_DIM + ocol + fr] = oacc[jj];
    }
    {
#pragma unroll
      for (int dt = 0; dt < 2; ++dt) {
        const int dk0 = (w * 2 + dt) * 16;
        f32x4 sacc;
#pragma unroll
        for (int jj = 0; jj < 4; ++jj) sacc[jj] = sreg[dt][jj] * eGC;
        const int dkr = dk0 + fr;
#pragma unroll
        for (int ks = 0; ks < 2; ++ks) {
          short8 xk;
#pragma unroll
          for (int e = 0; e < 8; ++e)
            xk[e] = (short)Klds[cb][kidx(ks * 32 + fq * 8 + e, dkr)];
          short8 yu = *(const short8*)&UTs[widx(fr, ks * 32 + fq * 8)];
          sacc = __builtin_amdgcn_mfma_f32_16x16x32_bf16(xk, yu, sacc, 0, 0, 0);
        }
#pragma unroll
        for (int jj = 0; jj < 4; ++jj) sreg[dt][jj] = sacc[jj];
      }
    }
    // no B4: next P1 writes only Klds[cb^1]/Wlds[cb^1]/Vlds/Sth/Stl/Th/Gs/Bsh
  }
}

// ---------------- gated RMSNorm -> bf16 (vectorized) ------------------------
__global__ __launch_bounds__(256) void gnorm_kernel(
    const float* __restrict__ o, const ushort* __restrict__ z,
    const float* __restrict__ gamma, ushort* __restrict__ ob) {
  const int row = blockIdx.x;
  const int t = threadIdx.x;
  const int grp = t >> 3, r = t & 7;
  const float* op = o + (size_t)row * VALUE_DIM + grp * DVH + r * 16;
  const ushort* zp = z + (size_t)row * VALUE_DIM + grp * DVH + r * 16;
  ushort* obp = ob + (size_t)row * VALUE_DIM + grp * DVH + r * 16;
  float4 ov[4];
  short8 zv[2];
#pragma unroll
  for (int q = 0; q < 4; ++q) ov[q] = *(const float4*)&op[q * 4];
  zv[0] = *(const short8*)&zp[0];
  zv[1] = *(const short8*)&zp[8];
  float vals[16];
  float ssq = 0.f;
#pragma unroll
  for (int i = 0; i < 16; ++i) {
    float zz = bfu((ushort)zv[i >> 3][i & 7]);
    float oo = ((const float*)&ov[i >> 2])[i & 3];
    float x = oo * (zz / (1.f + expf(-zz)));
    vals[i] = x;
    ssq += x * x;
  }
  ssq += __shfl_xor(ssq, 1, 64);
  ssq += __shfl_xor(ssq, 2, 64);
  ssq += __shfl_xor(ssq, 4, 64);
  float sc = rsqrtf(ssq * (1.f / 128.f) + 1e-6f);
  short8 o0, o1;
#pragma unroll
  for (int i = 0; i < 8; ++i) {
    o0[i] = (short)f2b(vals[i] * sc * gamma[r * 16 + i]);
    o1[i] = (short)f2b(vals[8 + i] * sc * gamma[r * 16 + 8 + i]);
  }
  *(short8*)&obp[0] = o0;
  *(short8*)&obp[8] = o1;
}

// ---------------------------------------------------------------------------
extern "C" void kernel_launch(void* const* d_in, const int* in_sizes, int n_in,
                              void* d_out, int out_size, void* d_ws,
                              size_t ws_size, hipStream_t stream) {
  const float* hs = (const float*)d_in[0];
  const float* w_qkv = (const float*)d_in[1];
  const float* w_z = (const float*)d_in[2];
  const float* w_b = (const float*)d_in[3];
  const float* w_a = (const float*)d_in[4];
  const float* conv_w = (const float*)d_in[5];
  const float* dt_bias = (const float*)d_in[6];
  const float* A_log = (const float*)d_in[7];
  const float* gamma = (const float*)d_in[8];
  const float* w_out = (const float*)d_in[9];
  float* out = (float*)d_out;
  char* wsb = (char*)d_ws;

  // workspace layout (241 MiB total)
  ushort* hs_b = (ushort*)wsb;                      // 16 MiB (later: Tbuf)
  ushort* wqkvT = hs_b + (size_t)MM * HSZ;          // 32 MiB (later: Wbuf)
  ushort* wzT = wqkvT + (size_t)CONV_DIM * HSZ;     // 16 MiB (contiguous w/ wqkvT)
  ushort* woutT = wzT + (size_t)VALUE_DIM * HSZ;    // 16 MiB
  ushort* mixed = woutT + (size_t)HSZ * VALUE_DIM;  // 64 MiB bf16
  ushort* qkv = mixed + (size_t)MM * CONV_DIM;      // 64 MiB bf16
  ushort* z = qkv + (size_t)MM * CONV_DIM;          // 32 MiB bf16
  float* gbuf = (float*)(z + (size_t)MM * VALUE_DIM);
  float* beta = gbuf + (size_t)MM * NUM_V_HEADS;
  float* o = (float*)mixed;   // fp32, aliases retired mixed (64 MiB)
  ushort* ob = qkv;           // bf16, aliases retired qkv
  ushort* Tbuf = hs_b;        // 16 MiB, aliases retired hs_b
  ushort* Wbuf = wqkvT;       // 16 MiB, fits in retired wqkvT (32 MiB)

  // one prep dispatch: cast(8192) + wqkvT(16384) + wzT(8192) + woutT(8192)
  prep_kernel<<<40960, 256, 0, stream>>>(hs, w_qkv, w_z, w_out, hs_b, wqkvT,
                                         wzT, woutT);

  // fused mixed+z GEMM: B = [wqkvT ; wzT] contiguous, N_total = 12288
  gemm256_fused<<<dim3((CONV_DIM + VALUE_DIM) / 256, MM / 256), 512, 0,
                  stream>>>(hs_b, wqkvT, mixed, z, MM, HSZ);
  ba_kernel<<<MM / 8, 256, 0, stream>>>(hs, w_b, w_a, dt_bias, A_log, gbuf,
                                        beta);
  conv_kernel<<<2048, 256, 0, stream>>>(mixed, conv_w, qkv);
  chunk_T_kernel<<<2048, 256, 0, stream>>>(qkv, gbuf, beta, Tbuf, Wbuf);
  recur_chunk_kernel<<<512, 256, 0, stream>>>(qkv, gbuf, beta, Tbuf, Wbuf, o);
  gnorm_kernel<<<MM, 256, 0, stream>>>(o, z, gamma, ob);
  gemm128_f32<<<dim3(HSZ / 128, MM / 128), 256, 0, stream>>>(
      ob, woutT, out, MM, HSZ, VALUE_DIM);
}

// Round 19
// 625.621 us; speedup vs baseline: 1.0841x; 1.0841x over previous
//
#include <hip/hip_runtime.h>
#include <hip/hip_bf16.h>
#include <cstdint>

// ---------------------------------------------------------------------------
// Qwen3.5 GatedDeltaNet — round 19 (consolidation):
//  * ba folded into prep_kernel (2-row staged, 20KB LDS union; same math)
//  * conv/gnorm: expf -> __expf, div -> v_rcp (silu/sigmoid fast path)
//  All else byte-identical to round 18 (678 us, absmax 0.0234).
// ---------------------------------------------------------------------------

#define HSZ 2048
#define NUM_K_HEADS 16
#define NUM_V_HEADS 32
#define DKH 128
#define DVH 128
#define KEY_DIM 2048
#define VALUE_DIM 4096
#define CONV_DIM 8192
#define BB 2
#define SSEQ 2048
#define MM (BB * SSEQ) /* 4096 rows */
#define CHUNK 64
#define NCHUNK (SSEQ / CHUNK) /* 32 */
#define DVB 16 /* v-cols per recur block */

typedef __hip_bfloat16 bf16;
typedef short short8 __attribute__((ext_vector_type(8)));
typedef float f32x4 __attribute__((ext_vector_type(4)));

__device__ __forceinline__ float bfu(ushort u) {
  union { float f; uint32_t i; } x;
  x.i = ((uint32_t)u) << 16;
  return x.f;
}
__device__ __forceinline__ ushort f2b(float f) {
  bf16 h = __float2bfloat16(f);
  return *reinterpret_cast<ushort*>(&h);
}
__device__ __forceinline__ float fsilu(float a) {
  return a * __builtin_amdgcn_rcpf(1.f + __expf(-a));
}

__device__ __forceinline__ void gload16(const void* g, const void* l) {
  __builtin_amdgcn_global_load_lds(
      (const __attribute__((address_space(1))) unsigned int*)g,
      (__attribute__((address_space(3))) unsigned int*)(const_cast<void*>(l)),
      16, 0, 0);
}

// swizzled LDS indexers (break D=128/D=64 row-major bank pathology)
__device__ __forceinline__ int kidx(int r, int d) {  // [*][128] bf16
  return r * 128 + (((d >> 3) ^ (r & 7)) << 3) + (d & 7);
}
__device__ __forceinline__ int widx(int r, int d) {  // [*][64] bf16
  return r * 64 + (((d >> 3) ^ (r & 7)) << 3) + (d & 7);
}

// ---------------- prep: cast hs + 3 transposes + ba (one dispatch) ---------
__device__ __forceinline__ void tc_tile(const float* __restrict__ W,
                                        ushort* __restrict__ WT, int K, int N,
                                        int n0, int k0, int t,
                                        ushort (*tile)[33]) {
  const int tx = t & 31, ty = t >> 5;
#pragma unroll
  for (int i = 0; i < 4; ++i)
    tile[ty + i * 8][tx] = f2b(W[(size_t)(k0 + ty + i * 8) * N + n0 + tx]);
  __syncthreads();
#pragma unroll
  for (int i = 0; i < 4; ++i)
    WT[(size_t)(n0 + ty + i * 8) * K + k0 + tx] = tile[tx][ty + i * 8];
}

__global__ __launch_bounds__(256) void prep_kernel(
    const float* __restrict__ hs, const float* __restrict__ w_qkv,
    const float* __restrict__ w_z, const float* __restrict__ w_out,
    const float* __restrict__ w_b, const float* __restrict__ w_a,
    const float* __restrict__ dt_bias, const float* __restrict__ A_log,
    ushort* __restrict__ hs_b, ushort* __restrict__ wqkvT,
    ushort* __restrict__ wzT, ushort* __restrict__ woutT,
    float* __restrict__ gbuf, float* __restrict__ beta) {
  __shared__ __align__(16) char shmem[20608];  // max(tile 2.1KB, ba 20KB)
  const int bid = blockIdx.x;
  const int t = threadIdx.x;
  if (bid < 8192) {  // cast: MM*HSZ/4 = 2M float4, exactly 8192 blocks
    const int i = bid * 256 + t;
    float4 v = ((const float4*)hs)[i];
    ushort4 u;
    u.x = f2b(v.x); u.y = f2b(v.y); u.z = f2b(v.z); u.w = f2b(v.w);
    ((ushort4*)hs_b)[i] = u;
  } else if (bid < 8192 + 16384) {  // w_qkv: [2048,8192] -> [8192,2048]
    const int idx = bid - 8192;
    tc_tile(w_qkv, wqkvT, HSZ, CONV_DIM, (idx & 255) * 32, (idx >> 8) * 32, t,
            (ushort(*)[33])shmem);
  } else if (bid < 8192 + 16384 + 8192) {  // w_z: [2048,4096] -> [4096,2048]
    const int idx = bid - 24576;
    tc_tile(w_z, wzT, HSZ, VALUE_DIM, (idx & 127) * 32, (idx >> 7) * 32, t,
            (ushort(*)[33])shmem);
  } else if (bid < 8192 + 16384 + 8192 + 8192) {  // w_out
    const int idx = bid - 32768;
    tc_tile(w_out, woutT, VALUE_DIM, HSZ, (idx & 63) * 32, (idx >> 6) * 32, t,
            (ushort(*)[33])shmem);
  } else {  // ba: 512 blocks x 8 rows, staged 2 rows/pass
    const int row0 = (bid - 40960) * 8;
    float* hsr2 = (float*)shmem;            // [2][2048] = 16 KB
    float* red = (float*)(shmem + 16384);   // [4][256]  = 4 KB
    const int h = t & 31, p = t >> 5;
    const int kbeg = p * 256;
#pragma unroll 1
    for (int pass = 0; pass < 4; ++pass) {
      const int r0 = row0 + pass * 2;
      const float4* src = (const float4*)(hs + (size_t)r0 * HSZ);
      for (int i = t; i < 1024; i += 256) ((float4*)hsr2)[i] = src[i];
      __syncthreads();
      float sb0 = 0.f, sa0 = 0.f, sb1 = 0.f, sa1 = 0.f;
      for (int k = kbeg; k < kbeg + 256; ++k) {
        float wb = w_b[k * NUM_V_HEADS + h];
        float wa = w_a[k * NUM_V_HEADS + h];
        sb0 += hsr2[k] * wb;
        sa0 += hsr2[k] * wa;
        sb1 += hsr2[2048 + k] * wb;
        sa1 += hsr2[2048 + k] * wa;
      }
      red[t] = sb0;
      red[256 + t] = sa0;
      red[512 + t] = sb1;
      red[768 + t] = sa1;
      __syncthreads();
      if (t < 64) {
        const int rr = t >> 5, hh = t & 31;
        float b = 0.f, a = 0.f;
#pragma unroll
        for (int q = 0; q < 8; ++q) {
          b += red[rr * 512 + hh + 32 * q];
          a += red[rr * 512 + 256 + hh + 32 * q];
        }
        float bet = 1.f / (1.f + expf(-b));
        float x = a + dt_bias[hh];
        float sp = (x > 20.f) ? x : log1pf(expf(x));
        gbuf[(size_t)(r0 + rr) * NUM_V_HEADS + hh] = -expf(A_log[hh]) * sp;
        beta[(size_t)(r0 + rr) * NUM_V_HEADS + hh] = bet;
      }
      __syncthreads();  // hsr2/red reused next pass
    }
  }
}

// ---------------- fused 256^2 bf16 MFMA GEMM (mixed | z) -------------------
// BK=32, 4-buffer ring, stage-in-compute-region, vmcnt(4), 1 barrier/tile.
__global__ __launch_bounds__(512) void gemm256_fused(
    const ushort* __restrict__ A, const ushort* __restrict__ BT,
    ushort* __restrict__ Cm, ushort* __restrict__ Cz, int M, int K) {
  __shared__ __align__(16) ushort smem[256 * 264];  // >= 4 bufs x 16384
  const int t = threadIdx.x;
  const int w = t >> 6, lane = t & 63;
  const int m0 = blockIdx.y * 256, n0 = blockIdx.x * 256;
  const int wm = (w >> 2) * 128, wn = (w & 3) * 64;
  const int fr = lane & 15, kb = lane >> 4;  // kb = k-granule 0..3
  const int srow = t >> 2;                   // 0..127
  const int sg = t & 3;                      // staging granule
  const int ssw = ((sg ^ ((srow >> 1) & 3)) << 3);  // pre-swizzled src col
  f32x4 acc[8][4] = {};
  const int nt = K / 32;

#define STAGE_F(tt, buf)                                                      \
  {                                                                           \
    const int k0_ = (tt)*32;                                                  \
    ushort* As_ = smem + (buf)*16384;                                         \
    ushort* Bs_ = As_ + 8192;                                                 \
    _Pragma("unroll") for (int p = 0; p < 2; ++p) {                           \
      const int row_ = p * 128 + srow;                                        \
      gload16(&A[(size_t)(m0 + row_) * K + k0_ + ssw],                        \
              &As_[row_ * 32 + sg * 8]);                                      \
    }                                                                         \
    _Pragma("unroll") for (int p = 0; p < 2; ++p) {                           \
      const int row_ = p * 128 + srow;                                        \
      gload16(&BT[(size_t)(n0 + row_) * K + k0_ + ssw],                       \
              &Bs_[row_ * 32 + sg * 8]);                                      \
    }                                                                         \
  }

  STAGE_F(0, 0);
  STAGE_F(1, 1);

  for (int tt = 0; tt < nt; ++tt) {
    const int buf = tt & 3;
    if (tt + 1 < nt)
      asm volatile("s_waitcnt vmcnt(4)" ::: "memory");
    else
      asm volatile("s_waitcnt vmcnt(0)" ::: "memory");
    __builtin_amdgcn_sched_barrier(0);
    __builtin_amdgcn_s_barrier();  // tile tt landed for all waves
    __builtin_amdgcn_sched_barrier(0);
    if (tt + 2 < nt) STAGE_F(tt + 2, (tt + 2) & 3);  // overlaps compute
    const ushort* As = smem + buf * 16384;
    const ushort* Bs = As + 8192;
    short8 af[8], bf_[4];
#pragma unroll
    for (int nf = 0; nf < 4; ++nf) {
      const int row = wn + nf * 16 + fr;
      bf_[nf] = *(const short8*)&Bs[row * 32 + ((kb ^ ((row >> 1) & 3)) << 3)];
    }
#pragma unroll
    for (int mf = 0; mf < 8; ++mf) {
      const int row = wm + mf * 16 + fr;
      af[mf] = *(const short8*)&As[row * 32 + ((kb ^ ((row >> 1) & 3)) << 3)];
    }
    __builtin_amdgcn_s_setprio(1);
#pragma unroll
    for (int mf = 0; mf < 8; ++mf)
#pragma unroll
      for (int nf = 0; nf < 4; ++nf)
        acc[mf][nf] = __builtin_amdgcn_mfma_f32_16x16x32_bf16(
            af[mf], bf_[nf], acc[mf][nf], 0, 0, 0);
    __builtin_amdgcn_s_setprio(0);
  }
#undef STAGE_F

  __syncthreads();  // all reads done before epilogue overwrites smem
  const int crow = wm + (lane >> 4) * 4;
  const int ccol = wn + fr;
#pragma unroll
  for (int mf = 0; mf < 8; ++mf)
#pragma unroll
    for (int nf = 0; nf < 4; ++nf)
#pragma unroll
      for (int j = 0; j < 4; ++j)
        smem[(crow + mf * 16 + j) * 264 + ccol + nf * 16] = f2b(acc[mf][nf][j]);
  __syncthreads();
  ushort* Cout = (n0 < CONV_DIM) ? Cm : Cz;
  const int Nout = (n0 < CONV_DIM) ? CONV_DIM : VALUE_DIM;
  const int ncol = (n0 < CONV_DIM) ? n0 : n0 - CONV_DIM;
#pragma unroll
  for (int p = 0; p < 16; ++p) {
    const int r = p * 16 + (t >> 5), cch = (t & 31) * 8;
    *(short8*)&Cout[(size_t)(m0 + r) * Nout + ncol + cch] =
        *(const short8*)&smem[r * 264 + cch];
  }
}

// ---------------- 128^2 bf16 MFMA GEMM (fp32 out), BK=32 4-buffer ring -----
__global__ __launch_bounds__(256, 2) void gemm128_f32(
    const ushort* __restrict__ A, const ushort* __restrict__ BT,
    float* __restrict__ C, int M, int N, int K) {
  __shared__ __align__(16) ushort smem[4 * 8192];  // 64 KiB
  const int t = threadIdx.x;
  const int w = t >> 6, lane = t & 63;
  const int m0 = blockIdx.y * 128, n0 = blockIdx.x * 128;
  const int wm = (w >> 1) * 64, wn = (w & 1) * 64;
  const int fr = lane & 15, kb = lane >> 4;
  const int srow = t >> 2;  // 0..63
  const int sg = t & 3;
  const int ssw = ((sg ^ ((srow >> 1) & 3)) << 3);
  f32x4 acc[4][4] = {};
  const int nt = K / 32;

#define STAGE_G(tt, buf)                                                      \
  {                                                                           \
    const int k0_ = (tt)*32;                                                  \
    ushort* As_ = smem + (buf)*8192;                                          \
    ushort* Bs_ = As_ + 4096;                                                 \
    _Pragma("unroll") for (int p = 0; p < 2; ++p) {                           \
      const int row_ = p * 64 + srow;                                         \
      gload16(&A[(size_t)(m0 + row_) * K + k0_ + ssw],                        \
              &As_[row_ * 32 + sg * 8]);                                      \
    }                                                                         \
    _Pragma("unroll") for (int p = 0; p < 2; ++p) {                           \
      const int row_ = p * 64 + srow;                                         \
      gload16(&BT[(size_t)(n0 + row_) * K + k0_ + ssw],                       \
              &Bs_[row_ * 32 + sg * 8]);                                      \
    }                                                                         \
  }

  STAGE_G(0, 0);
  STAGE_G(1, 1);

  for (int tt = 0; tt < nt; ++tt) {
    const int buf = tt & 3;
    if (tt + 1 < nt)
      asm volatile("s_waitcnt vmcnt(4)" ::: "memory");
    else
      asm volatile("s_waitcnt vmcnt(0)" ::: "memory");
    __builtin_amdgcn_sched_barrier(0);
    __builtin_amdgcn_s_barrier();
    __builtin_amdgcn_sched_barrier(0);
    if (tt + 2 < nt) STAGE_G(tt + 2, (tt + 2) & 3);
    const ushort* As = smem + buf * 8192;
    const ushort* Bs = As + 4096;
    short8 af[4], bfr[4];
#pragma unroll
    for (int nf = 0; nf < 4; ++nf) {
      const int row = wn + nf * 16 + fr;
      bfr[nf] = *(const short8*)&Bs[row * 32 + ((kb ^ ((row >> 1) & 3)) << 3)];
    }
#pragma unroll
    for (int mf = 0; mf < 4; ++mf) {
      const int row = wm + mf * 16 + fr;
      af[mf] = *(const short8*)&As[row * 32 + ((kb ^ ((row >> 1) & 3)) << 3)];
    }
    __builtin_amdgcn_s_setprio(1);
#pragma unroll
    for (int mf = 0; mf < 4; ++mf)
#pragma unroll
      for (int nf = 0; nf < 4; ++nf)
        acc[mf][nf] = __builtin_amdgcn_mfma_f32_16x16x32_bf16(
            af[mf], bfr[nf], acc[mf][nf], 0, 0, 0);
    __builtin_amdgcn_s_setprio(0);
  }
#undef STAGE_G

  const int orow = m0 + wm + (lane >> 4) * 4;
  const int ocol = n0 + wn + fr;
#pragma unroll
  for (int mf = 0; mf < 4; ++mf)
#pragma unroll
    for (int nf = 0; nf < 4; ++nf)
#pragma unroll
      for (int j = 0; j < 4; ++j)
        C[(size_t)(orow + mf * 16 + j) * N + ocol + nf * 16] = acc[mf][nf][j];
}

// ---------------- causal conv + silu + l2norm (row-tiled, rolling window) --
__global__ __launch_bounds__(256) void conv_kernel(
    const ushort* __restrict__ mixed, const float* __restrict__ conv_w,
    ushort* __restrict__ qkv) {
  const int bid = blockIdx.x;
  const int slice = bid & 3;
  const int row0 = (bid >> 2) * 8;
  const int s0 = row0 & (SSEQ - 1);
  const int t = threadIdx.x;
  const int cbase = slice * 2048 + t * 8;

  float wreg[4][8];
#pragma unroll
  for (int e = 0; e < 8; ++e) {
    float4 wv = *(const float4*)&conv_w[(cbase + e) * 4];
    wreg[0][e] = wv.x;
    wreg[1][e] = wv.y;
    wreg[2][e] = wv.z;
    wreg[3][e] = wv.w;
  }

  const ushort* mp = mixed + (size_t)row0 * CONV_DIM + cbase;
  short8 win[4];
  const short8 z8 = {0, 0, 0, 0, 0, 0, 0, 0};
#pragma unroll
  for (int j = 0; j < 3; ++j)
    win[j] = (s0 - 3 + j >= 0) ? *(const short8*)&mp[(ptrdiff_t)(j - 3) * CONV_DIM]
                               : z8;

  if (slice < 2) {
    float vals[8][8];
    float ssq[8];
#pragma unroll
    for (int r = 0; r < 8; ++r) {
      win[3] = *(const short8*)&mp[(ptrdiff_t)r * CONV_DIM];
      float sq = 0.f;
#pragma unroll
      for (int e = 0; e < 8; ++e) {
        float a = bfu((ushort)win[0][e]) * wreg[0][e] +
                  bfu((ushort)win[1][e]) * wreg[1][e] +
                  bfu((ushort)win[2][e]) * wreg[2][e] +
                  bfu((ushort)win[3][e]) * wreg[3][e];
        float x = fsilu(a);
        vals[r][e] = x;
        sq += x * x;
      }
      ssq[r] = sq;
      win[0] = win[1];
      win[1] = win[2];
      win[2] = win[3];
    }
#pragma unroll
    for (int r = 0; r < 8; ++r) {
      float sq = ssq[r];
      sq += __shfl_xor(sq, 1, 64);
      sq += __shfl_xor(sq, 2, 64);
      sq += __shfl_xor(sq, 4, 64);
      sq += __shfl_xor(sq, 8, 64);
      float sc = rsqrtf(sq + 1e-6f);
      if (slice == 0) sc *= 0.08838834764831845f;
      short8 o;
#pragma unroll
      for (int e = 0; e < 8; ++e) o[e] = (short)f2b(vals[r][e] * sc);
      *(short8*)&qkv[(size_t)(row0 + r) * CONV_DIM + cbase] = o;
    }
  } else {
#pragma unroll
    for (int r = 0; r < 8; ++r) {
      win[3] = *(const short8*)&mp[(ptrdiff_t)r * CONV_DIM];
      short8 o;
#pragma unroll
      for (int e = 0; e < 8; ++e) {
        float a = bfu((ushort)win[0][e]) * wreg[0][e] +
                  bfu((ushort)win[1][e]) * wreg[1][e] +
                  bfu((ushort)win[2][e]) * wreg[2][e] +
                  bfu((ushort)win[3][e]) * wreg[3][e];
        o[e] = (short)f2b(fsilu(a));
      }
      *(short8*)&qkv[(size_t)(row0 + r) * CONV_DIM + cbase] = o;
      win[0] = win[1];
      win[1] = win[2];
      win[2] = win[3];
    }
  }
}

// ---------------- stage 1: per-chunk T = (I+A)^{-1} and W ------------------
__global__ __launch_bounds__(256) void chunk_T_kernel(
    const ushort* __restrict__ qkv, const float* __restrict__ gbuf,
    const float* __restrict__ beta, ushort* __restrict__ Tbuf,
    ushort* __restrict__ Wbuf) {
  const int bid = blockIdx.x;
  const int c = bid & 31;
  const int h = (bid >> 5) & 31;
  const int b = bid >> 10;
  const int hk = h >> 1;
  const int t = threadIdx.x;
  const int w = t >> 6, lane = t & 63;
  const int fr = lane & 15, fq = lane >> 4;

  __shared__ ushort Klds[64 * 128];           // 16 KB
  __shared__ __align__(16) float AT[64][68];  // 17.4 KB
  __shared__ ushort Wlds[64 * 64];            // 8 KB
  __shared__ float Gs[64], Bsh[64];

  const int row0 = b * SSEQ + c * CHUNK;
  const int qcol = hk * DKH;
  const int kcol = KEY_DIM + hk * DKH;

  short8 xq[4];
#pragma unroll
  for (int ks = 0; ks < 4; ++ks)
    xq[ks] = *(const short8*)&qkv[(size_t)(row0 + w * 16 + fr) * CONV_DIM +
                                  qcol + ks * 32 + fq * 8];
#pragma unroll
  for (int r = 0; r < 4; ++r) {
    int vi = t + 256 * r;
    int row = vi >> 4, gr = vi & 15;
    *(short8*)&Klds[row * 128 + ((gr ^ (row & 7)) << 3)] =
        *(const short8*)&qkv[(size_t)(row0 + row) * CONV_DIM + kcol + gr * 8];
  }
  if (t < 64) {
    float s = gbuf[(size_t)(row0 + t) * NUM_V_HEADS + h];
#pragma unroll
    for (int off = 1; off < 64; off <<= 1) {
      float p = __shfl_up(s, off, 64);
      if (lane >= off) s += p;
    }
    Gs[t] = s;
    Bsh[t] = beta[(size_t)(row0 + t) * NUM_V_HEADS + h];
  }
  __syncthreads();

  f32x4 kkt[4] = {}, qkt[4] = {};
#pragma unroll
  for (int ks = 0; ks < 4; ++ks) {
    int d0 = ks * 32 + fq * 8;
    short8 xk = *(const short8*)&Klds[kidx(w * 16 + fr, d0)];
#pragma unroll
    for (int j = 0; j < 4; ++j) {
      short8 yk = *(const short8*)&Klds[kidx(j * 16 + fr, d0)];
      kkt[j] = __builtin_amdgcn_mfma_f32_16x16x32_bf16(xk, yk, kkt[j], 0, 0, 0);
      qkt[j] = __builtin_amdgcn_mfma_f32_16x16x32_bf16(xq[ks], yk, qkt[j], 0, 0, 0);
    }
  }
#pragma unroll
  for (int j = 0; j < 4; ++j)
#pragma unroll
    for (int jj = 0; jj < 4; ++jj) {
      int i = w * 16 + fq * 4 + jj;
      int jc = j * 16 + fr;
      AT[jc][i] = (jc < i) ? Bsh[i] * __expf(Gs[i] - Gs[jc]) * kkt[j][jj] : 0.f;
      float val = (jc <= i) ? __expf(Gs[i] - Gs[jc]) * qkt[j][jj] : 0.f;
      Wlds[widx(i, jc)] = f2b(val);
    }
  __syncthreads();

  {
    ushort* Wg = Wbuf + (size_t)bid * 4096;
#pragma unroll
    for (int e = 0; e < 8; ++e)
      ((uint*)Wg)[e * 256 + t] = ((const uint*)Wlds)[e * 256 + t];
  }

  if (w == 0) {
    float u[64];
#pragma unroll
    for (int i = 0; i < 64; ++i) u[i] = (i == lane) ? 1.f : 0.f;
#pragma unroll
    for (int j = 0; j < 63; ++j) {
      float xj = u[j];
      const int i0 = (j + 1) & ~3;
#pragma unroll
      for (int ii = i0; ii < 64; ii += 4) {
        float4 a4 = *(const float4*)&AT[j][ii];
        if (ii + 0 > j) u[ii + 0] -= a4.x * xj;
        if (ii + 1 > j) u[ii + 1] -= a4.y * xj;
        if (ii + 2 > j) u[ii + 2] -= a4.z * xj;
        if (ii + 3 > j) u[ii + 3] -= a4.w * xj;
      }
    }
    ushort* Tg = Tbuf + (size_t)bid * 4096;
#pragma unroll
    for (int i = 0; i < 64; ++i) Tg[i * 64 + lane] = f2b(u[i]);
  }
}

// ---------------- stage 2: sequential chunk loop, 3 barriers/chunk ---------
__global__ __launch_bounds__(256, 2) void recur_chunk_kernel(
    const ushort* __restrict__ qkv, const float* __restrict__ gbuf,
    const float* __restrict__ beta, const ushort* __restrict__ Tbuf,
    const ushort* __restrict__ Wbuf, float* __restrict__ o) {
  const int bid = blockIdx.x;
  const int dvq = bid & 7;
  const int h = (bid >> 3) & 31;
  const int b = bid >> 8;
  const int hk = h >> 1;
  const int t = threadIdx.x;
  const int w = t >> 6, lane = t & 63;
  const int fr = lane & 15, fq = lane >> 4;

  __shared__ ushort Klds[2][64 * 128];  // 32 KB (chunk-parity dbuf)
  __shared__ ushort Wlds[2][64 * 64];   // 16 KB (chunk-parity dbuf)
  __shared__ ushort Vlds[64 * DVB];     // 2 KB
  __shared__ ushort Sth[DVB * 128];     // 4 KB
  __shared__ ushort Stl[DVB * 128];     // 4 KB
  __shared__ ushort Th[64 * 64];        // 8 KB
  __shared__ ushort Ut[DVB * 64];       // 2 KB
  __shared__ ushort UTs[DVB * 64];      // 2 KB
  __shared__ ushort UTo[DVB * 64];      // 2 KB
  __shared__ float Gs[64], Bsh[64];

  float sreg[2][4] = {};

  const int qcol = hk * DKH;
  const int kcol = KEY_DIM + hk * DKH;
  const int vcol = 2 * KEY_DIM + h * DVH + dvq * DVB;
  const int ocol = h * DVH + dvq * DVB;
  const size_t tbase0 = ((size_t)(b * 32 + h) * 32) * 4096;

  short8 pK[4], pT0, pT1, pV, pxq[4];
  uint pW[8];
  float pg = 0.f, pb = 0.f;

  auto prefetch = [&](int c) {
    const int row0 = b * SSEQ + c * CHUNK;
#pragma unroll
    for (int ks = 0; ks < 4; ++ks)
      pxq[ks] = *(const short8*)&qkv[(size_t)(row0 + w * 16 + fr) * CONV_DIM +
                                     qcol + ks * 32 + fq * 8];
    const ushort* Tg = Tbuf + tbase0 + (size_t)c * 4096;
    const ushort* Wg = Wbuf + tbase0 + (size_t)c * 4096;
    pT0 = *(const short8*)&Tg[t * 16];
    pT1 = *(const short8*)&Tg[t * 16 + 8];
#pragma unroll
    for (int e = 0; e < 8; ++e) pW[e] = ((const uint*)Wg)[e * 256 + t];
#pragma unroll
    for (int r = 0; r < 4; ++r) {
      int vi = t + 256 * r;
      int row = vi >> 4, gr = vi & 15;
      pK[r] = *(const short8*)&qkv[(size_t)(row0 + row) * CONV_DIM + kcol + gr * 8];
    }
    if (t < 128) {
      int row = t >> 1, c0 = (t & 1) * 8;
      pV = *(const short8*)&qkv[(size_t)(row0 + row) * CONV_DIM + vcol + c0];
    }
    if (t < 64) {
      pg = gbuf[(size_t)(row0 + t) * NUM_V_HEADS + h];
      pb = beta[(size_t)(row0 + t) * NUM_V_HEADS + h];
    }
  };

  prefetch(0);

  for (int c = 0; c < NCHUNK; ++c) {
    const int row0 = b * SSEQ + c * CHUNK;
    const int cb = c & 1;

    short8 xq[4];
#pragma unroll
    for (int ks = 0; ks < 4; ++ks) xq[ks] = pxq[ks];
#pragma unroll
    for (int e = 0; e < 8; ++e) ((uint*)Wlds[cb])[e * 256 + t] = pW[e];
#pragma unroll
    for (int r = 0; r < 4; ++r) {
      int vi = t + 256 * r;
      int row = vi >> 4, gr = vi & 15;
      *(short8*)&Klds[cb][row * 128 + ((gr ^ (row & 7)) << 3)] = pK[r];
    }
    if (t < 128) {
      int row = t >> 1, c0 = (t & 1) * 8;
      *(short8*)&Vlds[row * DVB + c0] = pV;
    }
    if (t < 64) {
      float s = pg;
#pragma unroll
      for (int off = 1; off < 64; off <<= 1) {
        float p = __shfl_up(s, off, 64);
        if (lane >= off) s += p;
      }
      Gs[t] = s;
      Bsh[t] = pb;
    }
#pragma unroll
    for (int dt = 0; dt < 2; ++dt)
#pragma unroll
      for (int jj = 0; jj < 4; ++jj) {
        int d = (w * 2 + dt) * 16 + fq * 4 + jj;
        float f = sreg[dt][jj];
        ushort hi = f2b(f);
        int idx = kidx(fr, d);
        Sth[idx] = hi;
        Stl[idx] = f2b(f - bfu(hi));
      }
    {
      int r = t >> 2, d0 = (t & 3) * 16;
      *(short8*)&Th[widx(r, d0)] = pT0;
      *(short8*)&Th[widx(r, d0 + 8)] = pT1;
    }
    __syncthreads();  // B1

    if (c + 1 < NCHUNK) prefetch(c + 1);

    const float eGC = __expf(Gs[63]);

    f32x4 ks0 = {}, qs0 = {};
#pragma unroll
    for (int ks = 0; ks < 4; ++ks) {
      int d0 = ks * 32 + fq * 8;
      short8 xk = *(const short8*)&Klds[cb][kidx(w * 16 + fr, d0)];
      short8 yh = *(const short8*)&Sth[kidx(fr, d0)];
      short8 yl = *(const short8*)&Stl[kidx(fr, d0)];
      ks0 = __builtin_amdgcn_mfma_f32_16x16x32_bf16(xk, yh, ks0, 0, 0, 0);
      ks0 = __builtin_amdgcn_mfma_f32_16x16x32_bf16(xk, yl, ks0, 0, 0, 0);
      qs0 = __builtin_amdgcn_mfma_f32_16x16x32_bf16(xq[ks], yh, qs0, 0, 0, 0);
      qs0 = __builtin_amdgcn_mfma_f32_16x16x32_bf16(xq[ks], yl, qs0, 0, 0, 0);
    }
    f32x4 oacc;
#pragma unroll
    for (int jj = 0; jj < 4; ++jj) {
      int i = w * 16 + fq * 4 + jj;
      float eg = __expf(Gs[i]);
      float rhs = Bsh[i] * (bfu(Vlds[i * DVB + fr]) - eg * ks0[jj]);
      Ut[widx(fr, i)] = f2b(rhs);
      oacc[jj] = qs0[jj] * eg;
    }
    __syncthreads();  // B2

    {
      f32x4 uacc = {};
#pragma unroll
      for (int ks = 0; ks < 2; ++ks) {
        int j0 = ks * 32 + fq * 8;
        short8 ta = *(const short8*)&Th[widx(w * 16 + fr, j0)];
        short8 ub = *(const short8*)&Ut[widx(fr, j0)];
        uacc = __builtin_amdgcn_mfma_f32_16x16x32_bf16(ta, ub, uacc, 0, 0, 0);
      }
#pragma unroll
      for (int jj = 0; jj < 4; ++jj) {
        int i = w * 16 + fq * 4 + jj;
        float u = uacc[jj];
        UTo[widx(fr, i)] = f2b(u);
        UTs[widx(fr, i)] = f2b(u * __expf(Gs[63] - Gs[i]));
      }
    }
    __syncthreads();  // B3

#pragma unroll
    for (int ks = 0; ks < 2; ++ks) {
      int i0 = ks * 32 + fq * 8;
      short8 xw = *(const short8*)&Wlds[cb][widx(w * 16 + fr, i0)];
      short8 yu = *(const short8*)&UTo[widx(fr, i0)];
      oacc = __builtin_amdgcn_mfma_f32_16x16x32_bf16(xw, yu, oacc, 0, 0, 0);
    }
#pragma unroll
    for (int jj = 0; jj < 4; ++jj) {
      int tt = w * 16 + fq * 4 + jj;
      o[(size_t)(row0 + tt) * VALUE_DIM + ocol + fr] = oacc[jj];
    }
    {
#pragma unroll
      for (int dt = 0; dt < 2; ++dt) {
        const int dk0 = (w * 2 + dt) * 16;
        f32x4 sacc;
#pragma unroll
        for (int jj = 0; jj < 4; ++jj) sacc[jj] = sreg[dt][jj] * eGC;
        const int dkr = dk0 + fr;
#pragma unroll
        for (int ks = 0; ks < 2; ++ks) {
          short8 xk;
#pragma unroll
          for (int e = 0; e < 8; ++e)
            xk[e] = (short)Klds[cb][kidx(ks * 32 + fq * 8 + e, dkr)];
          short8 yu = *(const short8*)&UTs[widx(fr, ks * 32 + fq * 8)];
          sacc = __builtin_amdgcn_mfma_f32_16x16x32_bf16(xk, yu, sacc, 0, 0, 0);
        }
#pragma unroll
        for (int jj = 0; jj < 4; ++jj) sreg[dt][jj] = sacc[jj];
      }
    }
    // no B4: next P1 writes only the other parity's Klds/Wlds + scratch
  }
}

// ---------------- gated RMSNorm -> bf16 (vectorized, fast sigmoid) ----------
__global__ __launch_bounds__(256) void gnorm_kernel(
    const float* __restrict__ o, const ushort* __restrict__ z,
    const float* __restrict__ gamma, ushort* __restrict__ ob) {
  const int row = blockIdx.x;
  const int t = threadIdx.x;
  const int grp = t >> 3, r = t & 7;
  const float* op = o + (size_t)row * VALUE_DIM + grp * DVH + r * 16;
  const ushort* zp = z + (size_t)row * VALUE_DIM + grp * DVH + r * 16;
  ushort* obp = ob + (size_t)row * VALUE_DIM + grp * DVH + r * 16;
  float4 ov[4];
  short8 zv[2];
#pragma unroll
  for (int q = 0; q < 4; ++q) ov[q] = *(const float4*)&op[q * 4];
  zv[0] = *(const short8*)&zp[0];
  zv[1] = *(const short8*)&zp[8];
  float vals[16];
  float ssq = 0.f;
#pragma unroll
  for (int i = 0; i < 16; ++i) {
    float zz = bfu((ushort)zv[i >> 3][i & 7]);
    float oo = ((const float*)&ov[i >> 2])[i & 3];
    float x = oo * fsilu(zz);
    vals[i] = x;
    ssq += x * x;
  }
  ssq += __shfl_xor(ssq, 1, 64);
  ssq += __shfl_xor(ssq, 2, 64);
  ssq += __shfl_xor(ssq, 4, 64);
  float sc = rsqrtf(ssq * (1.f / 128.f) + 1e-6f);
  short8 o0, o1;
#pragma unroll
  for (int i = 0; i < 8; ++i) {
    o0[i] = (short)f2b(vals[i] * sc * gamma[r * 16 + i]);
    o1[i] = (short)f2b(vals[8 + i] * sc * gamma[r * 16 + 8 + i]);
  }
  *(short8*)&obp[0] = o0;
  *(short8*)&obp[8] = o1;
}

// ---------------------------------------------------------------------------
extern "C" void kernel_launch(void* const* d_in, const int* in_sizes, int n_in,
                              void* d_out, int out_size, void* d_ws,
                              size_t ws_size, hipStream_t stream) {
  const float* hs = (const float*)d_in[0];
  const float* w_qkv = (const float*)d_in[1];
  const float* w_z = (const float*)d_in[2];
  const float* w_b = (const float*)d_in[3];
  const float* w_a = (const float*)d_in[4];
  const float* conv_w = (const float*)d_in[5];
  const float* dt_bias = (const float*)d_in[6];
  const float* A_log = (const float*)d_in[7];
  const float* gamma = (const float*)d_in[8];
  const float* w_out = (const float*)d_in[9];
  float* out = (float*)d_out;
  char* wsb = (char*)d_ws;

  // workspace layout (241 MiB total)
  ushort* hs_b = (ushort*)wsb;                      // 16 MiB (later: Tbuf)
  ushort* wqkvT = hs_b + (size_t)MM * HSZ;          // 32 MiB (later: Wbuf)
  ushort* wzT = wqkvT + (size_t)CONV_DIM * HSZ;     // 16 MiB (contiguous w/ wqkvT)
  ushort* woutT = wzT + (size_t)VALUE_DIM * HSZ;    // 16 MiB
  ushort* mixed = woutT + (size_t)HSZ * VALUE_DIM;  // 64 MiB bf16
  ushort* qkv = mixed + (size_t)MM * CONV_DIM;      // 64 MiB bf16
  ushort* z = qkv + (size_t)MM * CONV_DIM;          // 32 MiB bf16
  float* gbuf = (float*)(z + (size_t)MM * VALUE_DIM);
  float* beta = gbuf + (size_t)MM * NUM_V_HEADS;
  float* o = (float*)mixed;   // fp32, aliases retired mixed (64 MiB)
  ushort* ob = qkv;           // bf16, aliases retired qkv
  ushort* Tbuf = hs_b;        // 16 MiB, aliases retired hs_b
  ushort* Wbuf = wqkvT;       // 16 MiB, fits in retired wqkvT (32 MiB)

  // one prep dispatch: cast(8192) + transposes(32768) + ba(512)
  prep_kernel<<<41472, 256, 0, stream>>>(hs, w_qkv, w_z, w_out, w_b, w_a,
                                         dt_bias, A_log, hs_b, wqkvT, wzT,
                                         woutT, gbuf, beta);

  // fused mixed+z GEMM: B = [wqkvT ; wzT] contiguous, N_total = 12288
  gemm256_fused<<<dim3((CONV_DIM + VALUE_DIM) / 256, MM / 256), 512, 0,
                  stream>>>(hs_b, wqkvT, mixed, z, MM, HSZ);
  conv_kernel<<<2048, 256, 0, stream>>>(mixed, conv_w, qkv);
  chunk_T_kernel<<<2048, 256, 0, stream>>>(qkv, gbuf, beta, Tbuf, Wbuf);
  recur_chunk_kernel<<<512, 256, 0, stream>>>(qkv, gbuf, beta, Tbuf, Wbuf, o);
  gnorm_kernel<<<MM, 256, 0, stream>>>(o, z, gamma, ob);
  gemm128_f32<<<dim3(HSZ / 128, MM / 128), 256, 0, stream>>>(
      ob, woutT, out, MM, HSZ, VALUE_DIM);
}